// Round 10
// baseline (179.696 us; speedup 1.0000x reference)
//
#include <hip/hip_runtime.h>
#include <math.h>

// VectorQuantizer via MFMA: in [32,64,64,64] fp32 NCHW (C=D=64), w [512,64] fp32.
// R9 post-mortem: main=73us but pipe sums ~25us -- wave-starved (4096 waves =
// 16/CU cap; JIT B-load latency uncovered). R10: K-split x2 -- each wave does
// 32 queries x half the codebook (16 tiles) -> 8192 waves (32/CU cap), total
// B traffic UNCHANGED. Block = 128 thr = the 2 K-half waves of one query
// group; cross-half merge via LDS + 1 barrier (R2-verified lex shape).
// Also: 6 MFMAs chained into ONE acc (init 0; kills accP+accQ add),
// launch_bounds(128,6). Fold / butterfly / tau-re-rank verbatim from R9.
typedef short bf16x8 __attribute__((ext_vector_type(8)));
typedef float f32x4 __attribute__((ext_vector_type(4)));

#define VQ_D 64
#define VQ_K 512
#define VQ_NQ 131072
#define VQ_TOTAL 8388608
#define NTH 16           // B tiles per K-half (32 total)
#define TAU 8e-3f

__device__ __forceinline__ ushort bf16_rne(float f) {
    uint u = __builtin_bit_cast(uint, f);
    u += 0x7fffu + ((u >> 16) & 1u);
    return (ushort)(u >> 16);
}
__device__ __forceinline__ float bf16_to_f(ushort h) {
    uint u = ((uint)h) << 16;
    return __builtin_bit_cast(float, u);
}

// ---- prep: w -> bf16 hi/lo in MFMA B-fragment order + fp32 norms + loss=0 ----
// (verbatim R6-R9, passed)
__global__ __launch_bounds__(128) void vq_prep(const float* __restrict__ w,
                                               ushort* __restrict__ wfrag,
                                               float* __restrict__ wn,
                                               float* __restrict__ out) {
    if (blockIdx.x == 0 && threadIdx.x == 0) out[VQ_TOTAL] = 0.f;
    const int k = blockIdx.x * 128 + threadIdx.x;   // one code per thread
    const float4* row = (const float4*)(w + k * VQ_D);
    const int t = k >> 4, col = k & 15;
    float nrm = 0.f;
    for (int g = 0; g < 8; ++g) {                   // granule g: d in [g*8, g*8+8)
        float4 a = row[2 * g], b4 = row[2 * g + 1];
        float v[8] = {a.x, a.y, a.z, a.w, b4.x, b4.y, b4.z, b4.w};
        ushort hi[8], lo[8];
#pragma unroll
        for (int j = 0; j < 8; ++j) {
            nrm = fmaf(v[j], v[j], nrm);
            hi[j] = bf16_rne(v[j]);
            lo[j] = bf16_rne(v[j] - bf16_to_f(hi[j]));
        }
        const int quad = g & 3, fh = g >> 2;
        const int lane = quad * 16 + col;
        bf16x8* basez = (bf16x8*)wfrag + t * 256 + lane;
        *(basez + fh * 64)       = *(bf16x8*)hi;    // bh{fh}
        *(basez + (2 + fh) * 64) = *(bf16x8*)lo;    // bl{fh}
    }
    wn[k] = nrm;
}

__global__ __launch_bounds__(128, 6) void vq_main(const float* __restrict__ in,
                                                  const float* __restrict__ w,
                                                  const ushort* __restrict__ wfrag,
                                                  const float* __restrict__ wng,
                                                  float* __restrict__ out) {
    __shared__ uint4 mrg_lds[2][32];   // per K-half: (bD bits, bI, sD bits, sI) per query
    __shared__ float xn_lds[32];
    __shared__ int   bi_lds[32];

    const int tid  = threadIdx.x;
    const int lane = tid & 63;
    const int half = tid >> 6;          // which K-half this wave scans
    const int col  = lane & 15;
    const int quad = lane >> 4;
    const int n0  = blockIdx.x * 32;    // block's 32 queries
    const int b   = n0 >> 12;
    const int hw0 = n0 & 4095;
    const float* xg0 = in + (b << 18) + hw0;

    // ---- A fragments direct from global (verbatim R9; both waves same 32 q) ----
    bf16x8 ah0[2], ah1[2], al0[2], al1[2];
#pragma unroll
    for (int T = 0; T < 2; ++T) {
        const float* xq = xg0 + T * 16 + col;
        float sx = 0.f;
        ushort h0[8], l0[8], h1[8], l1[8];
#pragma unroll
        for (int j = 0; j < 8; ++j) {
            float v0 = xq[(quad * 8 + j) << 12];        // kstep0: d in [0,32)
            float v1 = xq[(32 + quad * 8 + j) << 12];   // kstep1: d in [32,64)
            sx = fmaf(v0, v0, sx);
            sx = fmaf(v1, v1, sx);
            h0[j] = bf16_rne(v0); l0[j] = bf16_rne(v0 - bf16_to_f(h0[j]));
            h1[j] = bf16_rne(v1); l1[j] = bf16_rne(v1 - bf16_to_f(h1[j]));
        }
        ah0[T] = *(bf16x8*)h0; al0[T] = *(bf16x8*)l0;
        ah1[T] = *(bf16x8*)h1; al1[T] = *(bf16x8*)l1;
        sx += __shfl_xor(sx, 16, 64);                   // sum the 4 quads
        sx += __shfl_xor(sx, 32, 64);
        if (quad == 0 && half == 0) xn_lds[T * 16 + col] = sx;
    }

    // ---- K-loop over this wave's half: 6 MFMAs chained into one acc ----
    float best[8], sec[8];
#pragma unroll
    for (int r = 0; r < 8; ++r) { best[r] = 3.0e38f; sec[r] = 3.0e38f; }

    const bf16x8* wfb = (const bf16x8*)wfrag + lane + half * (NTH * 256);

#pragma unroll 1
    for (int tl = 0; tl < NTH; ++tl) {
        const int tg = half * NTH + tl;                // global tile
        const bf16x8* wf = wfb + tl * 256;
        const bf16x8 bh0 = wf[0], bh1 = wf[64], bl0 = wf[128], bl1 = wf[192];
        const float wnv = wng[tg * 16 + col];
#pragma unroll
        for (int T = 0; T < 2; ++T) {
            f32x4 acc = {0.f, 0.f, 0.f, 0.f};
            acc = __builtin_amdgcn_mfma_f32_16x16x32_bf16(ah0[T], bh0, acc, 0, 0, 0);
            acc = __builtin_amdgcn_mfma_f32_16x16x32_bf16(ah1[T], bh1, acc, 0, 0, 0);
            acc = __builtin_amdgcn_mfma_f32_16x16x32_bf16(ah0[T], bl0, acc, 0, 0, 0);
            acc = __builtin_amdgcn_mfma_f32_16x16x32_bf16(ah1[T], bl1, acc, 0, 0, 0);
            acc = __builtin_amdgcn_mfma_f32_16x16x32_bf16(al0[T], bh0, acc, 0, 0, 0);
            acc = __builtin_amdgcn_mfma_f32_16x16x32_bf16(al1[T], bh1, acc, 0, 0, 0);
#pragma unroll
            for (int j = 0; j < 4; ++j) {          // C: row(query)=quad*4+j, col=code
                float dist = fmaf(-2.f, acc[j], wnv);
                uint u = (__builtin_bit_cast(uint, dist) & 0xFFFFFFE0u) | (uint)tg;
                float key = __builtin_bit_cast(float, u);
                const int r = T * 4 + j;
                float m = fmaxf(best[r], key);
                best[r] = fminf(best[r], key);
                sec[r]  = fminf(sec[r], m);
            }
        }
    }

    // ---- unpack packed keys (verbatim R9) ----
    float bD[8], sD[8];
    int bI[8], sI[8];
#pragma unroll
    for (int r = 0; r < 8; ++r) {
        uint ub = __builtin_bit_cast(uint, best[r]);
        uint us = __builtin_bit_cast(uint, sec[r]);
        bI[r] = (int)(ub & 31u) * 16 + col;
        sI[r] = (int)(us & 31u) * 16 + col;
        bD[r] = __builtin_bit_cast(float, ub & 0xFFFFFFE0u);
        sD[r] = __builtin_bit_cast(float, us & 0xFFFFFFE0u);
    }

    // ---- butterfly merge across 16 col-lanes (verbatim R9) ----
#pragma unroll
    for (int off = 1; off < 16; off <<= 1) {
#pragma unroll
        for (int r = 0; r < 8; ++r) {
            float ob = __shfl_xor(bD[r], off, 64);
            float os = __shfl_xor(sD[r], off, 64);
            int   oi = __shfl_xor(bI[r], off, 64);
            int   oc = __shfl_xor(sI[r], off, 64);
            bool oWins = (ob < bD[r]) || (ob == bD[r] && oi < bI[r]);
            float nb  = oWins ? ob    : bD[r];
            int   ni  = oWins ? oi    : bI[r];
            float c1  = oWins ? bD[r] : ob;      // loser's best
            int   ci1 = oWins ? bI[r] : oi;
            float c2  = oWins ? os    : sD[r];   // winner's second
            int   ci2 = oWins ? oc    : sI[r];
            bool c1w = (c1 < c2) || (c1 == c2 && ci1 < ci2);
            sD[r] = c1w ? c1  : c2;
            sI[r] = c1w ? ci1 : ci2;
            bD[r] = nb; bI[r] = ni;
        }
    }
    if (col == 0) {
#pragma unroll
        for (int r = 0; r < 8; ++r) {           // q = T*16 + quad*4 + j  in [0,32)
            const int q = (r >> 2) * 16 + quad * 4 + (r & 3);
            mrg_lds[half][q] = make_uint4(__builtin_bit_cast(uint, bD[r]), (uint)bI[r],
                                          __builtin_bit_cast(uint, sD[r]), (uint)sI[r]);
        }
    }
    __syncthreads();

    // ---- wave 0: cross-half lex merge + fp64 near-tie re-rank + loss ----
    if (half == 0) {
        const int q = lane;                      // lanes 0..31 active for re-rank
        float cb = 0.f, cs = 0.f;
        int cbi = 0, csi = 0;
        double lq = 0.0;
        if (lane < 32) {
            uint4 A = mrg_lds[0][q], B = mrg_lds[1][q];
            float da = __builtin_bit_cast(float, A.x), db_ = __builtin_bit_cast(float, B.x);
            float sa = __builtin_bit_cast(float, A.z), sb = __builtin_bit_cast(float, B.z);
            int ia = (int)A.y, ib = (int)B.y, ja = (int)A.w, jb = (int)B.w;
            bool aw = (da < db_) || (da == db_ && ia < ib);
            cb  = aw ? da : db_;  cbi = aw ? ia : ib;
            float c1  = aw ? db_ : da;  int ci1 = aw ? ib : ia;   // loser's best
            float c2  = aw ? sa  : sb;  int ci2 = aw ? ja : jb;   // winner's second
            bool c1w = (c1 < c2) || (c1 == c2 && ci1 < ci2);
            cs  = c1w ? c1  : c2;
            csi = c1w ? ci1 : ci2;

            double chosen = (double)cb;
            if (cs - cb < TAU) {                 // verbatim R9 re-rank
                const float* wb  = w + cbi * VQ_D;
                const float* ws2 = w + csi * VQ_D;
                const float* xqp = xg0 + q;
                double nb = 0.0, dotb = 0.0, ns = 0.0, dots = 0.0;
                for (int d = 0; d < VQ_D; ++d) {
                    double xv = (double)xqp[d << 12];
                    double wbv = (double)wb[d], wsv = (double)ws2[d];
                    nb = fma(wbv, wbv, nb); dotb = fma(xv, wbv, dotb);
                    ns = fma(wsv, wsv, ns); dots = fma(xv, wsv, dots);
                }
                double db2 = nb - 2.0 * dotb, ds2 = ns - 2.0 * dots;
                if (ds2 < db2 || (ds2 == db2 && csi < cbi)) { cbi = csi; chosen = ds2; }
                else                                        { chosen = db2; }
            }
            bi_lds[q] = cbi;
            lq = (double)xn_lds[q] + chosen;     // ||x-e||^2 = xnorm + (wn - 2 dot)
        }
#pragma unroll
        for (int off = 32; off > 0; off >>= 1)
            lq += __shfl_down(lq, off, 64);
        if (lane == 0)
            atomicAdd(out + VQ_TOTAL, (float)(lq * (1.0 / (double)VQ_TOTAL)));
    }
    __syncthreads();

    // ---- cooperative quantized write: 4 threads/query, d-quarter each ----
    {
        const int q = tid & 31, u4 = tid >> 5;   // u4 covers d in [16*u4, 16*u4+16)
        const float4* wrow = (const float4*)(w + bi_lds[q] * VQ_D) + u4 * 4;
        float* op = out + (b << 18) + hw0 + q;
#pragma unroll
        for (int u = 0; u < 4; ++u) {
            float4 v = wrow[u];
            const int d = u4 * 16 + 4 * u;
            op[(d + 0) << 12] = v.x;
            op[(d + 1) << 12] = v.y;
            op[(d + 2) << 12] = v.z;
            op[(d + 3) << 12] = v.w;
        }
    }
}

extern "C" void kernel_launch(void* const* d_in, const int* in_sizes, int n_in,
                              void* d_out, int out_size, void* d_ws, size_t ws_size,
                              hipStream_t stream) {
    const float* in = (const float*)d_in[0];
    const float* w  = (const float*)d_in[1];
    float* out = (float*)d_out;

    ushort* wfrag = (ushort*)d_ws;                    // 512*128 ushort = 128 KB
    float*  wn    = (float*)((char*)d_ws + 131072);   // 512 floats

    vq_prep<<<4, 128, 0, stream>>>(w, wfrag, wn, out);   // also zeroes loss cell
    vq_main<<<VQ_NQ / 32, 128, 0, stream>>>(in, w, wfrag, wn, out);
}